// Round 2
// baseline (994.731 us; speedup 1.0000x reference)
//
#include <hip/hip_runtime.h>
#include <hip/hip_bf16.h>

// vector types matching MFMA register counts
typedef __bf16 bf16x8 __attribute__((ext_vector_type(8)));   // 4 VGPRs (A/B frag)
typedef float  f32x4  __attribute__((ext_vector_type(4)));   // 4 VGPRs (C/D frag)

// async global->LDS, 16B per lane. LDS dest = wave-uniform base + lane*16.
__device__ __forceinline__ void async_copy16(const void* gsrc, void* ldst) {
  __builtin_amdgcn_global_load_lds(
      (__attribute__((address_space(1))) void*)(gsrc),
      (__attribute__((address_space(3))) void*)(ldst),
      16, 0, 0);
}

// ---------------------------------------------------------------------------
// Cast all five fp32 tensors to bf16 scratch in one launch.
// Chunk = 8 elements. Region boundaries (in chunks):
//   enc_out 51200 | pred_out 25600 | enc_w 32768 | pred_w 32768 | out_w 131072
// cum: 51200, 76800, 109568, 142336, 273408  (= 1068 * 256 exactly)
// ---------------------------------------------------------------------------
__global__ __launch_bounds__(256) void cast_all(
    const float* __restrict__ s0, const float* __restrict__ s1,
    const float* __restrict__ s2, const float* __restrict__ s3,
    const float* __restrict__ s4,
    __bf16* __restrict__ d0, __bf16* __restrict__ d1, __bf16* __restrict__ d2,
    __bf16* __restrict__ d3, __bf16* __restrict__ d4) {
  const int c = blockIdx.x * 256 + threadIdx.x;
  const float* s; __bf16* d; int off;
  if (c < 51200)       { s = s0; d = d0; off = c; }
  else if (c < 76800)  { s = s1; d = d1; off = c - 51200; }
  else if (c < 109568) { s = s2; d = d2; off = c - 76800; }
  else if (c < 142336) { s = s3; d = d3; off = c - 109568; }
  else                 { s = s4; d = d4; off = c - 142336; }
  const float4* sp = (const float4*)(s + (size_t)off * 8);
  const float4 a = sp[0], b = sp[1];
  bf16x8 o;
  o[0] = (__bf16)a.x; o[1] = (__bf16)a.y; o[2] = (__bf16)a.z; o[3] = (__bf16)a.w;
  o[4] = (__bf16)b.x; o[5] = (__bf16)b.y; o[6] = (__bf16)b.z; o[7] = (__bf16)b.w;
  *(bf16x8*)(d + (size_t)off * 8) = o;
}

// ---------------------------------------------------------------------------
// NT GEMM: C[m,n] = sum_k A[m,k]*B[n,k] + bias[n]   (A,B bf16; bias,C fp32)
// A: [M,K] row-major, B: [N,K] row-major, K mult of 64, N mult of 128,
// M arbitrary (loads clamped, stores guarded).
// 128x128 tile, BK=64, 256 threads = 4 waves (2x2), wave = 4x4 grid of
// v_mfma_f32_16x16x32_bf16.
// LDS: 1024 16B chunks; chunk q holds global (row=q>>3, kc=(q&7)^(row&7)).
// XOR swizzle on the GLOBAL side (global_load_lds needs lane-contiguous LDS);
// keeps global reads in one 128B row segment, frag ds_read_b128 <=2-way
// conflicted (free, m136).
// ---------------------------------------------------------------------------
__global__ __launch_bounds__(256, 2) void gemm_bias_nt(
    const __bf16* __restrict__ A, const __bf16* __restrict__ B,
    const float* __restrict__ bias, float* __restrict__ C,
    int M, int N, int K) {
  const int tid  = threadIdx.x;
  const int wave = tid >> 6;
  const int lane = tid & 63;
  const int quad = lane >> 4;
  const int l16  = lane & 15;
  const int bn = blockIdx.x;   // n fastest: co-resident cohort shares A-tile
  const int bm = blockIdx.y;

  __shared__ __bf16 sA[128 * 64];
  __shared__ __bf16 sB[128 * 64];

  f32x4 acc[4][4];
#pragma unroll
  for (int i = 0; i < 4; ++i)
#pragma unroll
    for (int j = 0; j < 4; ++j) {
      acc[i][j][0] = 0.f; acc[i][j][1] = 0.f;
      acc[i][j][2] = 0.f; acc[i][j][3] = 0.f;
    }

  const int wm = (wave >> 1) * 64;
  const int wn = (wave & 1) * 64;

  const int nK = K >> 6;
  for (int kt = 0; kt < nK; ++kt) {
    const int k0 = kt << 6;
#pragma unroll
    for (int i = 0; i < 4; ++i) {
      const int f   = i * 256 + tid;        // chunk this lane fetches
      const int row = f >> 3;
      const int kc  = (f & 7) ^ (row & 7);  // XOR swizzle (global side)
      int ar = bm * 128 + row; if (ar >= M) ar = M - 1;  // clamp: no fault
      const __bf16* gA = A + (size_t)ar * K + k0 + kc * 8;
      async_copy16((const void*)gA, (void*)(sA + (i * 256 + wave * 64) * 8));
      const int br = bn * 128 + row;        // N mult of 128: in bounds
      const __bf16* gB = B + (size_t)br * K + k0 + kc * 8;
      async_copy16((const void*)gB, (void*)(sB + (i * 256 + wave * 64) * 8));
    }
    __syncthreads();  // compiler emits s_waitcnt vmcnt(0) before s_barrier

#pragma unroll
    for (int ks = 0; ks < 2; ++ks) {
      bf16x8 af[4], bfr[4];
#pragma unroll
      for (int mi = 0; mi < 4; ++mi) {
        const int row = wm + mi * 16 + l16;
        const int cc  = (ks * 4 + quad) ^ (row & 7);
        af[mi] = *(const bf16x8*)(sA + (row * 8 + cc) * 8);
      }
#pragma unroll
      for (int ni = 0; ni < 4; ++ni) {
        const int row = wn + ni * 16 + l16;
        const int cc  = (ks * 4 + quad) ^ (row & 7);
        bfr[ni] = *(const bf16x8*)(sB + (row * 8 + cc) * 8);
      }
#pragma unroll
      for (int mi = 0; mi < 4; ++mi)
#pragma unroll
        for (int ni = 0; ni < 4; ++ni)
          acc[mi][ni] = __builtin_amdgcn_mfma_f32_16x16x32_bf16(
              af[mi], bfr[ni], acc[mi][ni], 0, 0, 0);
    }
    __syncthreads();
  }

  // epilogue: C/D layout n = lane&15, m = quad*4 + reg  (m89-verified)
#pragma unroll
  for (int ni = 0; ni < 4; ++ni) {
    const int n = bn * 128 + wn + ni * 16 + l16;
    const float bs = bias[n];
#pragma unroll
    for (int mi = 0; mi < 4; ++mi) {
      const int mbase = bm * 128 + wm + mi * 16 + quad * 4;
#pragma unroll
      for (int r = 0; r < 4; ++r) {
        const int m = mbase + r;
        if (m < M) C[(size_t)m * N + n] = acc[mi][ni][r] + bs;
      }
    }
  }
}

// ---------------------------------------------------------------------------
// joint: h[row,:] = bf16(tanh(e[row/100,:] + p[(row/20000)*100 + row%100,:]))
// 8 elems/thread. e/p tiny (2.4MB) -> L2-hot. tanh(x)=1-2/(exp2(2x*log2e)+1);
// endpoints exact (+-1).
// ---------------------------------------------------------------------------
__global__ __launch_bounds__(256) void joint_tanh(
    const float* __restrict__ e, const float* __restrict__ p,
    __bf16* __restrict__ h) {
  const int chunk = blockIdx.x * 256 + threadIdx.x;  // [0, 80000*64)
  const int row = chunk >> 6;          // (b*200+t)*100 + u
  const int kc  = chunk & 63;
  const int er  = row / 100;           // b*200 + t
  const int b   = row / 20000;
  const int u   = row - er * 100;
  const int pr  = b * 100 + u;

  const float4* ep = (const float4*)(e + (size_t)er * 512 + kc * 8);
  const float4* pp = (const float4*)(p + (size_t)pr * 512 + kc * 8);
  const float4 e0 = ep[0], e1 = ep[1];
  const float4 p0 = pp[0], p1 = pp[1];

  const float x[8] = {e0.x + p0.x, e0.y + p0.y, e0.z + p0.z, e0.w + p0.w,
                      e1.x + p1.x, e1.y + p1.y, e1.z + p1.z, e1.w + p1.w};
  bf16x8 o;
#pragma unroll
  for (int i = 0; i < 8; ++i) {
    const float t  = __builtin_amdgcn_exp2f(x[i] * 2.8853900817779268f);
    const float th = 1.f - 2.f * __builtin_amdgcn_rcpf(t + 1.f);
    o[i] = (__bf16)th;
  }
  *(bf16x8*)(h + (size_t)chunk * 8) = o;
}

// ---------------------------------------------------------------------------
extern "C" void kernel_launch(void* const* d_in, const int* in_sizes, int n_in,
                              void* d_out, int out_size, void* d_ws,
                              size_t ws_size, hipStream_t stream) {
  const float* enc_out  = (const float*)d_in[0];  // [4,200,512] fp32
  const float* pred_out = (const float*)d_in[1];  // [4,100,512]
  const float* enc_w    = (const float*)d_in[2];  // [512,512]
  const float* enc_b    = (const float*)d_in[3];  // [512]
  const float* pred_w   = (const float*)d_in[4];  // [512,512]
  const float* pred_b   = (const float*)d_in[5];  // [512]
  const float* out_w    = (const float*)d_in[6];  // [2048,512]
  const float* out_b    = (const float*)d_in[7];  // [2048]
  float* out = (float*)d_out;                     // [4,200,100,2048] fp32

  char* ws = (char*)d_ws;   // total use: ~88.8 MB
  __bf16* h       = (__bf16*)ws;                    // 80000*512*2 = 81,920,000
  float*  e       = (float*)(ws + 81920000);        // 800*512*4   =  1,638,400
  float*  p       = (float*)(ws + 83558400);        // 400*512*4   =    819,200
  __bf16* enc16   = (__bf16*)(ws + 84377600);       // 409600*2    =    819,200
  __bf16* pred16  = (__bf16*)(ws + 85196800);       // 204800*2    =    409,600
  __bf16* encw16  = (__bf16*)(ws + 85606400);       // 262144*2    =    524,288
  __bf16* predw16 = (__bf16*)(ws + 86130688);       // 262144*2    =    524,288
  __bf16* outw16  = (__bf16*)(ws + 86654976);       // 1048576*2   =  2,097,152

  const dim3 blk(256);
  // 0) cast fp32 inputs -> bf16 scratch
  hipLaunchKernelGGL(cast_all, dim3(1068), blk, 0, stream,
                     enc_out, pred_out, enc_w, pred_w, out_w,
                     enc16, pred16, encw16, predw16, outw16);
  // 1) e = enc_out @ enc_w^T + enc_b   (M=800, N=512, K=512)
  hipLaunchKernelGGL(gemm_bias_nt, dim3(4, 7), blk, 0, stream,
                     enc16, encw16, enc_b, e, 800, 512, 512);
  // 2) p = pred_out @ pred_w^T + pred_b (M=400, N=512, K=512)
  hipLaunchKernelGGL(gemm_bias_nt, dim3(4, 4), blk, 0, stream,
                     pred16, predw16, pred_b, p, 400, 512, 512);
  // 3) h = bf16(tanh(e + p)), [80000, 512]
  hipLaunchKernelGGL(joint_tanh, dim3(20000), blk, 0, stream, e, p, h);
  // 4) out = h @ out_w^T + out_b  (M=80000, N=2048, K=512)
  hipLaunchKernelGGL(gemm_bias_nt, dim3(16, 625), blk, 0, stream,
                     h, outw16, out_b, out, 80000, 2048, 512);
}